// Round 8
// baseline (319.638 us; speedup 1.0000x reference)
//
#include <hip/hip_runtime.h>

// Problem constants (fixed instance): all float tensors are float32 on device.
#define NPL   16384        // nodes per level
#define DIM   64
#define CPN   8            // children per node
#define EPL   (NPL * CPN)  // edges per level block = 131072
#define NLEV  8

#define TPB   512
#define WPB   (TPB / 64)   // 8 waves per block

// ---- coherent (write-through, L2-bypassing) accessors (proven R6/R7):
// sc0 sc1 ops hit the memory-side coherent path; zero cache-maintenance
// instructions anywhere in the kernel.
__device__ __forceinline__ float co_ld(const float* p) {
    return __hip_atomic_load(p, __ATOMIC_RELAXED, __HIP_MEMORY_SCOPE_AGENT);
}
__device__ __forceinline__ void co_st(float* p, float v) {
    __hip_atomic_store(p, v, __ATOMIC_RELAXED, __HIP_MEMORY_SCOPE_AGENT);
}

__device__ __forceinline__ void load_wrow(float* dst, const float* W, int row) {
    const float4* p = (const float4*)(W + row * DIM);
    #pragma unroll
    for (int q = 0; q < DIM / 4; ++q) {
        float4 v = p[q];
        dst[4*q+0] = v.x; dst[4*q+1] = v.y;
        dst[4*q+2] = v.z; dst[4*q+3] = v.w;
    }
}

// tanh via hardware exp + rcp. |err| ~1e-6, threshold is 5.9e-2.
__device__ __forceinline__ float fast_tanh(float z) {
    z = fminf(15.f, fmaxf(-15.f, z));
    float e = __expf(-2.f * z);
    return (1.f - e) * __builtin_amdgcn_rcpf(1.f + e);
}

// Monotonic grid barrier (R6, proven): no fences, no cache walks.
__device__ __forceinline__ void gridbar(int* cnt, int target) {
    __syncthreads();
    if (threadIdx.x == 0) {
        __hip_atomic_fetch_add(cnt, 1, __ATOMIC_RELAXED,
                               __HIP_MEMORY_SCOPE_AGENT);
        while (__hip_atomic_load(cnt, __ATOMIC_RELAXED,
                                 __HIP_MEMORY_SCOPE_AGENT) < target)
            __builtin_amdgcn_s_sleep(2);
    }
    asm volatile("" ::: "memory");
    __syncthreads();
}

// ------------- Phase A: out[g] = x[g] @ Wr^T for ALL 131072 rows -----------
// Level-0 rows are final; level>=1 rows pre-stage the root term, consumed by
// the SAME wave in phase B (and only gathered by others one level later,
// after phase B finalizes them -> race-free).
template<int CB, bool COH>
__device__ __forceinline__ void phaseA(
    const float* __restrict__ x, const float* __restrict__ Wr,
    float* __restrict__ out, int lane, int w, int blk, float* sX4)
{
    constexpr int NPB = NPL / CB;          // nodes/block/level
    constexpr int NPW = NPB / WPB;         // nodes/wave/level (4 or 8)
    constexpr int GPL = NPW / 4;           // 4-row groups per level
    constexpr int NG  = NLEV * GPL;        // total groups for this wave

    float wr[DIM];
    load_wrow(wr, Wr, lane);

    const int base = blk * NPB + w * NPW;
    const int sub  = lane >> 4;            // row within 4-row group
    const int col4 = (lane & 15) * 4;      // dim offset of this lane's float4

    float4 q0, q1, q2;
    #define ROWB(g) ((long)((g) / GPL) * NPL + base + ((g) % GPL) * 4)
    q0 = *(const float4*)&x[(ROWB(0) + sub) * DIM + col4];
    if (NG > 1) q1 = *(const float4*)&x[(ROWB(1) + sub) * DIM + col4];

    #pragma unroll
    for (int g = 0; g < NG; ++g) {
        if (g + 2 < NG)
            q2 = *(const float4*)&x[(ROWB(g + 2) + sub) * DIM + col4];

        *(float4*)&sX4[sub * DIM + col4] = q0;  // stage 4 rows (in-order DS)

        const long rb = ROWB(g);
        #pragma unroll
        for (int rr = 0; rr < 4; ++rr) {
            float a0 = 0.f, a1 = 0.f, a2 = 0.f, a3 = 0.f;
            const float4* A = (const float4*)&sX4[rr * DIM];   // broadcast
            #pragma unroll
            for (int k = 0; k < DIM / 4; ++k) {
                float4 av = A[k];
                a0 += av.x * wr[4*k+0];
                a1 += av.y * wr[4*k+1];
                a2 += av.z * wr[4*k+2];
                a3 += av.w * wr[4*k+3];
            }
            float r = (a0 + a1) + (a2 + a3);
            float* d = &out[(rb + rr) * DIM + lane];
            if (COH) co_st(d, r); else *d = r;
        }
        q0 = q1; q1 = q2;
    }
    #undef ROWB
}

// -------- Phase B: out[g] = tanh(out[g] + agg·Wl^T + b) for one level ------
// vidx: lane l holds child index (pbase*CPN + (l & (NPW*CPN-1))), preloaded
// at kernel start. Gathers + self-row pipelined 2 nodes deep.
template<int CB, bool COH>
__device__ __forceinline__ void phaseB(
    int vidx, float* __restrict__ out,
    const float* wl, float bias, int L, int lane, int w, int blk, float* sA)
{
    constexpr int NPB = NPL / CB;
    constexpr int NPW = NPB / WPB;
    const int  pbase = blk * NPB + w * NPW;
    const long gbase = (long)L * NPL;

    float g0[CPN], g1[CPN], g2[CPN];
    float xr0, xr1, xr2;

    #define ISSUE(c, gg, xr)                                                  \
        {                                                                     \
            _Pragma("unroll")                                                 \
            for (int j = 0; j < CPN; ++j) {                                   \
                int s = __builtin_amdgcn_readlane(vidx, (c) * CPN + j);       \
                const float* p = &out[(long)s * DIM + lane];                  \
                gg[j] = COH ? co_ld(p) : *p;                                  \
            }                                                                 \
            {                                                                 \
                const float* p = &out[(gbase + pbase + (c)) * DIM + lane];    \
                xr = COH ? co_ld(p) : *p;                                     \
            }                                                                 \
        }

    ISSUE(0, g0, xr0);
    if (NPW > 1) ISSUE(1, g1, xr1);

    #pragma unroll
    for (int c = 0; c < NPW; ++c) {
        if (c + 2 < NPW) ISSUE(c + 2, g2, xr2);

        float agg = 0.f;
        #pragma unroll
        for (int j = 0; j < CPN; ++j) agg += g0[j];
        sA[lane] = agg;                            // per-wave slot, in-order DS

        float a0 = 0.f, a1 = 0.f, a2 = 0.f, a3 = bias + xr0;
        const float4* B = (const float4*)sA;       // broadcast: conflict-free
        #pragma unroll
        for (int k = 0; k < DIM / 4; ++k) {
            float4 bv = B[k];
            a0 += bv.x * wl[4*k+0];
            a1 += bv.y * wl[4*k+1];
            a2 += bv.z * wl[4*k+2];
            a3 += bv.w * wl[4*k+3];
        }
        float r = fast_tanh((a0 + a1) + (a2 + a3));
        float* d = &out[(gbase + pbase + c) * DIM + lane];
        if (COH) co_st(d, r); else *d = r;

        #pragma unroll
        for (int j = 0; j < CPN; ++j) { g0[j] = g1[j]; g1[j] = g2[j]; }
        xr0 = xr1; xr1 = xr2;
    }
    #undef ISSUE
}

// ---------------- Fused cooperative kernel (1 dispatch) ----------------
template<int CB>
__global__ __launch_bounds__(TPB, 4) void dag_fused(
    const float* __restrict__ x, const int* __restrict__ src,
    const float* __restrict__ Wl, const float* __restrict__ bl,
    const float* __restrict__ Wr, float* __restrict__ out,
    float* __restrict__ ws)
{
    __shared__ __align__(16) float sbuf[WPB][256];

    constexpr int NPB  = NPL / CB;
    constexpr int NPW  = NPB / WPB;
    constexpr int NIDX = NPW * CPN;        // 32 or 64

    const int lane = threadIdx.x & 63;
    const int w    = threadIdx.x >> 6;
    int* barcnt = (int*)ws;

    // Preload ALL levels' child indices (one coalesced load per level):
    // idx-load latency never touches the per-level critical path.
    const int pbase = blockIdx.x * NPB + w * NPW;
    int vidx[NLEV - 1];
    #pragma unroll
    for (int L = 1; L < NLEV; ++L)
        vidx[L - 1] = src[(long)(L - 1) * EPL + pbase * CPN + (lane & (NIDX - 1))];

    phaseA<CB, true>(x, Wr, out, lane, w, blockIdx.x, sbuf[w]);
    gridbar(barcnt, CB);

    float wl[DIM];
    load_wrow(wl, Wl, lane);
    const float bias = bl[lane];

    #pragma unroll
    for (int L = 1; L < NLEV; ++L) {
        phaseB<CB, true>(vidx[L - 1], out, wl, bias, L, lane, w,
                         blockIdx.x, sbuf[w]);
        if (L + 1 < NLEV)
            gridbar(barcnt, (L + 1) * CB);
    }
}

// ---------------- Fallback: normal launches (kernel-boundary coherence) ----
__global__ __launch_bounds__(TPB) void dag_phaseA_k(
    const float* __restrict__ x, const float* __restrict__ Wr,
    float* __restrict__ out)
{
    __shared__ __align__(16) float sbuf[WPB][256];
    const int lane = threadIdx.x & 63;
    const int w    = threadIdx.x >> 6;
    phaseA<512, false>(x, Wr, out, lane, w, blockIdx.x, sbuf[w]);
}

__global__ __launch_bounds__(TPB) void dag_phaseB_k(
    const int* __restrict__ src, const float* __restrict__ Wl,
    const float* __restrict__ bl, float* __restrict__ out, int L)
{
    __shared__ __align__(16) float sbuf[WPB][256];
    const int lane = threadIdx.x & 63;
    const int w    = threadIdx.x >> 6;
    constexpr int NPB = NPL / 512, NPW = NPB / WPB, NIDX = NPW * CPN;
    const int pbase = blockIdx.x * NPB + w * NPW;
    int vidx = src[(long)(L - 1) * EPL + pbase * CPN + (lane & (NIDX - 1))];
    float wl[DIM];
    load_wrow(wl, Wl, lane);
    phaseB<512, false>(vidx, out, wl, bl[lane], L, lane, w,
                       blockIdx.x, sbuf[w]);
}

extern "C" void kernel_launch(void* const* d_in, const int* in_sizes, int n_in,
                              void* d_out, int out_size, void* d_ws, size_t ws_size,
                              hipStream_t stream) {
    const float* x  = (const float*)d_in[0];   // [131072,64] f32
    const int*   ei = (const int*)d_in[1];     // [2, 917504] int32
    const float* Wl = (const float*)d_in[2];   // [64,64] f32
    const float* bl = (const float*)d_in[3];   // [64]    f32
    const float* Wr = (const float*)d_in[4];   // [64,64] f32
    float* out = (float*)d_out;                // [131072,64] f32
    float* ws  = (float*)d_ws;                 // [0..63]=barrier counter

    const int* src = ei;                       // first E entries = src row

    // Zero the barrier counter inside the captured work (d_ws is re-poisoned
    // 0xAA before every timed launch).
    hipMemsetAsync(ws, 0, 256, stream);

    void* args[] = {(void*)&x, (void*)&src, (void*)&Wl, (void*)&bl,
                    (void*)&Wr, (void*)&out, (void*)&ws};

    // Preferred: 512 blocks (2 blocks/CU, 4 waves/SIMD).
    hipError_t e = hipLaunchCooperativeKernel((const void*)dag_fused<512>,
                                              dim3(512), dim3(TPB),
                                              args, 0, stream);
    if (e != hipSuccess) {
        (void)hipGetLastError();
        // Known-good: 256 blocks (1 block/CU) — R7 configuration.
        e = hipLaunchCooperativeKernel((const void*)dag_fused<256>,
                                       dim3(256), dim3(TPB), args, 0, stream);
    }
    if (e != hipSuccess) {
        (void)hipGetLastError();
        // Last resort: per-level normal launches.
        hipLaunchKernelGGL(dag_phaseA_k, dim3(512), dim3(TPB), 0, stream,
                           x, Wr, out);
        for (int L = 1; L < NLEV; ++L) {
            hipLaunchKernelGGL(dag_phaseB_k, dim3(512), dim3(TPB), 0, stream,
                               src, Wl, bl, out, L);
        }
    }
}

// Round 10
// 222.834 us; speedup vs baseline: 1.4344x; 1.4344x over previous
//
#include <hip/hip_runtime.h>

// Problem constants (fixed instance): all float tensors are float32 on device.
#define NPL   16384        // nodes per level
#define DIM   64
#define CPN   8            // children per node
#define EPL   (NPL * CPN)  // edges per level block = 131072
#define NLEV  8

#define TPB     512
#define WPB     (TPB / 64)        // 8 waves per block
#define CBLOCKS 256               // 1 block/CU (R7 proven best; 512 regressed R8)
#define NPB     (NPL / CBLOCKS)   // 64 nodes per block per level
#define NPW     (NPB / WPB)       // 8 nodes per wave per level

// ---- write-through store (L2-bypassing, proven R6/R7): keeps L2 free of
// pre-final out data, so normal cached GATHER loads are safe (out lines enter
// L1/L2 only via our own post-final gathers). No cache-maintenance ops.
__device__ __forceinline__ void co_st(float* p, float v) {
    __hip_atomic_store(p, v, __ATOMIC_RELAXED, __HIP_MEMORY_SCOPE_AGENT);
}

__device__ __forceinline__ void load_wrow(float* dst, const float* W, int row) {
    const float4* p = (const float4*)(W + row * DIM);
    #pragma unroll
    for (int q = 0; q < DIM / 4; ++q) {
        float4 v = p[q];
        dst[4*q+0] = v.x; dst[4*q+1] = v.y;
        dst[4*q+2] = v.z; dst[4*q+3] = v.w;
    }
}

// tanh via hardware exp + rcp. |err| ~1e-6, threshold is 5.9e-2.
__device__ __forceinline__ float fast_tanh(float z) {
    z = fminf(15.f, fmaxf(-15.f, z));
    float e = __expf(-2.f * z);
    return (1.f - e) * __builtin_amdgcn_rcpf(1.f + e);
}

// Monotonic grid barrier (R6, proven): no fences, no cache walks.
// __syncthreads() drains vmcnt first, so all write-through stores of this
// block are at the coherent point before the arrive.
__device__ __forceinline__ void gridbar(int* cnt, int target) {
    __syncthreads();
    if (threadIdx.x == 0) {
        __hip_atomic_fetch_add(cnt, 1, __ATOMIC_RELAXED,
                               __HIP_MEMORY_SCOPE_AGENT);
        while (__hip_atomic_load(cnt, __ATOMIC_RELAXED,
                                 __HIP_MEMORY_SCOPE_AGENT) < target)
            __builtin_amdgcn_s_sleep(2);
    }
    asm volatile("" ::: "memory");
    __syncthreads();
}

// ------------- Phase A: x @ Wr^T for ALL 131072 rows -----------------------
// Level-0 rows go straight to out (final values; gathered cross-block later
// -> write-through). Levels 1-7 go to XR in d_ws: produced and consumed by
// the SAME wave -> normal cached path (same-XCD L2, coherent).
template<bool COH>
__device__ __forceinline__ void phaseA(
    const float* __restrict__ x, const float* __restrict__ Wr,
    float* __restrict__ out, float* __restrict__ XR,
    int lane, int w, int blk, float* sX4)
{
    constexpr int GPL = NPW / 4;           // 4-row groups per level (2)
    constexpr int NG  = NLEV * GPL;        // 16 groups total per wave

    float wr[DIM];
    load_wrow(wr, Wr, lane);

    const int base = blk * NPB + w * NPW;
    const int sub  = lane >> 4;            // row within 4-row group
    const int col4 = (lane & 15) * 4;      // dim offset of this lane's float4

    float4 q0, q1, q2;
    #define ROWB(g) ((long)((g) / GPL) * NPL + base + ((g) % GPL) * 4)
    q0 = *(const float4*)&x[(ROWB(0) + sub) * DIM + col4];
    q1 = *(const float4*)&x[(ROWB(1) + sub) * DIM + col4];

    #pragma unroll
    for (int g = 0; g < NG; ++g) {
        if (g + 2 < NG)
            q2 = *(const float4*)&x[(ROWB(g + 2) + sub) * DIM + col4];

        *(float4*)&sX4[sub * DIM + col4] = q0;  // stage 4 rows (in-order DS)

        const long rb = ROWB(g);
        const int  L  = g / GPL;
        #pragma unroll
        for (int rr = 0; rr < 4; ++rr) {
            float a0 = 0.f, a1 = 0.f, a2 = 0.f, a3 = 0.f;
            const float4* A = (const float4*)&sX4[rr * DIM];   // broadcast
            #pragma unroll
            for (int k = 0; k < DIM / 4; ++k) {
                float4 av = A[k];
                a0 += av.x * wr[4*k+0];
                a1 += av.y * wr[4*k+1];
                a2 += av.z * wr[4*k+2];
                a3 += av.w * wr[4*k+3];
            }
            float r = (a0 + a1) + (a2 + a3);
            const long gg = rb + rr;
            if (L == 0) {
                float* d = &out[gg * DIM + lane];
                if (COH) co_st(d, r); else *d = r;
            } else {
                XR[gg * DIM + lane] = r;          // same-wave consumer: cached
            }
        }
        q0 = q1; q1 = q2;
    }
    #undef ROWB
}

// -------- Phase B: out[g] = tanh(XR[g] + agg·Wl^T + b) for one level -------
// vidx: lane l holds child index of node (pbase + l/8), slot (l%8), preloaded
// at kernel start. Gathers are NORMAL CACHED loads (~7/8 L2-hit). Stores are
// write-through. 4-SLOT ring, prefetch distance 3: issue slot (c+3)&3 can
// never collide with consume slot c&3 (R9's fatal (c+3)%3==c%3 bug fixed).
template<bool COH>
__device__ __forceinline__ void phaseB(
    int vidx, const float* __restrict__ XR, float* __restrict__ out,
    const float* wl, float bias, int L, int lane, int w, int blk, float* sA)
{
    const int  pbase = blk * NPB + w * NPW;
    const long gbase = (long)L * NPL;

    float g[4][CPN];
    float xr[4];

    #define ISSUE(c, s)                                                       \
        {                                                                     \
            _Pragma("unroll")                                                 \
            for (int j = 0; j < CPN; ++j) {                                   \
                int si = __builtin_amdgcn_readlane(vidx, (c) * CPN + j);      \
                g[s][j] = out[(long)si * DIM + lane];   /* cached gather */   \
            }                                                                 \
            xr[s] = XR[(gbase + pbase + (c)) * DIM + lane];                   \
        }

    ISSUE(0, 0);
    ISSUE(1, 1);
    ISSUE(2, 2);

    #pragma unroll
    for (int c = 0; c < NPW; ++c) {
        const int slot = c & 3;
        if (c + 3 < NPW) ISSUE(c + 3, (c + 3) & 3);   // != slot, always

        // Tree-sum the 8 children (3-deep instead of 8-deep chain).
        float s0 = g[slot][0] + g[slot][1];
        float s1 = g[slot][2] + g[slot][3];
        float s2 = g[slot][4] + g[slot][5];
        float s3 = g[slot][6] + g[slot][7];
        float agg = (s0 + s1) + (s2 + s3);
        sA[lane] = agg;                            // per-wave slot, in-order DS

        float a0 = 0.f, a1 = 0.f, a2 = 0.f, a3 = bias + xr[slot];
        const float4* B = (const float4*)sA;       // broadcast: conflict-free
        #pragma unroll
        for (int k = 0; k < DIM / 4; ++k) {
            float4 bv = B[k];
            a0 += bv.x * wl[4*k+0];
            a1 += bv.y * wl[4*k+1];
            a2 += bv.z * wl[4*k+2];
            a3 += bv.w * wl[4*k+3];
        }
        float r = fast_tanh((a0 + a1) + (a2 + a3));
        float* d = &out[(gbase + pbase + c) * DIM + lane];
        if (COH) co_st(d, r); else *d = r;
    }
    #undef ISSUE
}

// ---------------- Fused cooperative kernel (1 dispatch) ----------------
__global__ __launch_bounds__(TPB, 2) void dag_fused(
    const float* __restrict__ x, const int* __restrict__ src,
    const float* __restrict__ Wl, const float* __restrict__ bl,
    const float* __restrict__ Wr, float* __restrict__ out,
    float* __restrict__ ws)
{
    __shared__ __align__(16) float sbuf[WPB][256];

    const int lane = threadIdx.x & 63;
    const int w    = threadIdx.x >> 6;

    int*   barcnt = (int*)ws;
    float* XR     = ws + 64;     // 256 B offset; 33.5 MB region in d_ws

    // Preload ALL levels' child indices (one coalesced load each): idx-load
    // latency never touches the per-level critical path.
    const int pbase = blockIdx.x * NPB + w * NPW;
    int vidx[NLEV - 1];
    #pragma unroll
    for (int L = 1; L < NLEV; ++L)
        vidx[L - 1] = src[(long)(L - 1) * EPL + pbase * CPN + lane];

    phaseA<true>(x, Wr, out, XR, lane, w, blockIdx.x, sbuf[w]);
    gridbar(barcnt, CBLOCKS);

    float wl[DIM];
    load_wrow(wl, Wl, lane);
    const float bias = bl[lane];

    #pragma unroll
    for (int L = 1; L < NLEV; ++L) {
        phaseB<true>(vidx[L - 1], XR, out, wl, bias, L, lane, w,
                     blockIdx.x, sbuf[w]);
        if (L + 1 < NLEV)
            gridbar(barcnt, (L + 1) * CBLOCKS);
    }
}

// ---------------- Fallback: normal launches (kernel-boundary coherence) ----
__global__ __launch_bounds__(TPB) void dag_phaseA_k(
    const float* __restrict__ x, const float* __restrict__ Wr,
    float* __restrict__ out, float* __restrict__ ws)
{
    __shared__ __align__(16) float sbuf[WPB][256];
    const int lane = threadIdx.x & 63;
    const int w    = threadIdx.x >> 6;
    phaseA<false>(x, Wr, out, ws + 64, lane, w, blockIdx.x, sbuf[w]);
}

__global__ __launch_bounds__(TPB) void dag_phaseB_k(
    const int* __restrict__ src, const float* __restrict__ Wl,
    const float* __restrict__ bl, float* __restrict__ out,
    float* __restrict__ ws, int L)
{
    __shared__ __align__(16) float sbuf[WPB][256];
    const int lane = threadIdx.x & 63;
    const int w    = threadIdx.x >> 6;
    const int pbase = blockIdx.x * NPB + w * NPW;
    int vidx = src[(long)(L - 1) * EPL + pbase * CPN + lane];
    float wl[DIM];
    load_wrow(wl, Wl, lane);
    phaseB<false>(vidx, ws + 64, out, wl, bl[lane], L, lane, w,
                  blockIdx.x, sbuf[w]);
}

extern "C" void kernel_launch(void* const* d_in, const int* in_sizes, int n_in,
                              void* d_out, int out_size, void* d_ws, size_t ws_size,
                              hipStream_t stream) {
    const float* x  = (const float*)d_in[0];   // [131072,64] f32
    const int*   ei = (const int*)d_in[1];     // [2, 917504] int32
    const float* Wl = (const float*)d_in[2];   // [64,64] f32
    const float* bl = (const float*)d_in[3];   // [64]    f32
    const float* Wr = (const float*)d_in[4];   // [64,64] f32
    float* out = (float*)d_out;                // [131072,64] f32
    float* ws  = (float*)d_ws;                 // [0..63]=barrier, [64..]=XR

    const int* src = ei;                       // first E entries = src row

    // Zero the barrier counter inside the captured work (d_ws is re-poisoned
    // 0xAA before every timed launch). XR needs no init (fully overwritten).
    hipMemsetAsync(ws, 0, 256, stream);

    void* args[] = {(void*)&x, (void*)&src, (void*)&Wl, (void*)&bl,
                    (void*)&Wr, (void*)&out, (void*)&ws};
    hipError_t e = hipLaunchCooperativeKernel((const void*)dag_fused,
                                              dim3(CBLOCKS), dim3(TPB),
                                              args, 0, stream);
    if (e != hipSuccess) {
        (void)hipGetLastError();               // clear sticky error
        hipLaunchKernelGGL(dag_phaseA_k, dim3(CBLOCKS), dim3(TPB), 0, stream,
                           x, Wr, out, ws);
        for (int L = 1; L < NLEV; ++L) {
            hipLaunchKernelGGL(dag_phaseB_k, dim3(CBLOCKS), dim3(TPB), 0, stream,
                               src, Wl, bl, out, ws, L);
        }
    }
}